// Round 3
// baseline (69.918 us; speedup 1.0000x reference)
//
#include <hip/hip_runtime.h>

#define SEQ 1024

typedef __attribute__((ext_vector_type(2))) float f2;

// LDS row layout: row k starts at word k*8 + (k>>4)*4.
// Stage-2 access: lane L, iter i reads key k = L*16+i -> word 132*L + 8*i.
// Bank start = (4L + 8i) mod 32: each 8-lane group {L, L+8, ...} tiles all 32
// banks exactly once with its 4-bank-wide b128 -> conflict-free (b128 floor).
// Within the loop the address is linear in i (step 8 words) since k>>4 == L.
static __device__ __forceinline__ int lds_addr(int k) {
    return (k << 3) + ((k >> 4) << 2);
}

// Closed-form qlayer for one token row y[0..7]:
// effective angles a = {y0+t0, y1+t1, y2+y3+t2, t3, y4+t4, y5+t5, y6+t6, y7+t7}
// c_w = cos(a_w);  out[0] = c1..c7, out[w] = c0..cw (w>=1).
static __device__ __forceinline__ void qrow(const float th[8], const float y[8], float o[8]) {
    float a[8];
    a[0] = y[0] + th[0];
    a[1] = y[1] + th[1];
    a[2] = y[2] + y[3] + th[2];
    a[3] = th[3];
    a[4] = y[4] + th[4];
    a[5] = y[5] + th[5];
    a[6] = y[6] + th[6];
    a[7] = y[7] + th[7];
    float c[8];
#pragma unroll
    for (int w = 0; w < 8; ++w) c[w] = __cosf(a[w]);
    o[1] = c[0] * c[1];
#pragma unroll
    for (int w = 2; w < 8; ++w) o[w] = o[w - 1] * c[w];
    float s = c[7];
#pragma unroll
    for (int w = 6; w >= 1; --w) s *= c[w];
    o[0] = s;
}

// Fused qlayer -> 2-head attention (dk=4) -> qlayer.
// Grid: 16 batches * 64 query-tiles = 1024 blocks, 256 threads (4 blocks/CU).
// Stage 1: block recomputes h[b] (1024x8) into LDS.
// Stage 2 (query-register-blocked): each WAVE owns 4 queries; each LANE owns a
//   16-key chunk (64 lanes cover all 1024 keys). Per key-row read (2x b128)
//   the thread computes 4 queries x 2 heads -> 4x less LDS traffic than
//   1-query-per-thread (the R2 bottleneck: 512 MB LDS reads -> now 134 MB).
//   Scores bounded (|h|<=1) -> unnormalized softmax, exp2 with 0.5*log2(e)
//   folded into Q. Full 64-lane butterfly reduces 40 partials; lanes 0..3 mux
//   out their query (branch-free cndmask) and store.
__global__ __launch_bounds__(256, 4) void mhaq_fused(const float* __restrict__ x,
                                                     const float* __restrict__ theta,
                                                     float* __restrict__ out) {
    __shared__ __align__(16) float h_lds[8448];  // max lds_addr(1023)+8 = 8444 words, 33.8 KB

    const int b   = blockIdx.x >> 6;         // batch
    const int qof = (blockIdx.x & 63) << 4;  // first query of this block's 16-query tile
    const int t   = threadIdx.x;

    float th[8];
#pragma unroll
    for (int w = 0; w < 8; ++w) th[w] = theta[w];

    // ---- Stage 1: h[b] into LDS ----
    const float4* xb = (const float4*)(x + (size_t)b * SEQ * 8);
    float4 v0[4], v1[4];
#pragma unroll
    for (int r = 0; r < 4; ++r) {  // issue all 8 global loads up front
        const int k = t + (r << 8);
        v0[r] = xb[2 * k];
        v1[r] = xb[2 * k + 1];
    }
#pragma unroll
    for (int r = 0; r < 4; ++r) {
        const int k = t + (r << 8);
        const float y[8] = {v0[r].x, v0[r].y, v0[r].z, v0[r].w,
                            v1[r].x, v1[r].y, v1[r].z, v1[r].w};
        float o[8];
        qrow(th, y, o);
        float4* p = (float4*)&h_lds[lds_addr(k)];
        p[0] = make_float4(o[0], o[1], o[2], o[3]);
        p[1] = make_float4(o[4], o[5], o[6], o[7]);
    }
    __syncthreads();

    // ---- Stage 2: attention, 4 queries per wave ----
    const int lane  = t & 63;
    const int wv    = t >> 6;
    const int qbase = qof + (wv << 2);

    // Q scaled by 1/sqrt(dk)*log2(e) so softmax exp is a single v_exp_f32.
    const float qscale = 0.5f * 1.44269504f;
    f2 qv[4][4];
#pragma unroll
    for (int qq = 0; qq < 4; ++qq) {
        const float* qp = &h_lds[lds_addr(qbase + qq)];  // broadcast read (all lanes same row)
        qv[qq][0] = f2{qp[0], qp[1]} * qscale;
        qv[qq][1] = f2{qp[2], qp[3]} * qscale;
        qv[qq][2] = f2{qp[4], qp[5]} * qscale;
        qv[qq][3] = f2{qp[6], qp[7]} * qscale;
    }

    float l0[4] = {0.f, 0.f, 0.f, 0.f};
    float l1[4] = {0.f, 0.f, 0.f, 0.f};
    f2 a01[4], a23[4], a45[4], a67[4];
#pragma unroll
    for (int qq = 0; qq < 4; ++qq) {
        a01[qq] = f2{0.f, 0.f};
        a23[qq] = f2{0.f, 0.f};
        a45[qq] = f2{0.f, 0.f};
        a67[qq] = f2{0.f, 0.f};
    }

    int base = lds_addr(lane << 4);  // = 132*lane; linear (+8) within the chunk
#pragma unroll 4
    for (int i = 0; i < 16; ++i) {
        const float4 k0 = *(const float4*)&h_lds[base];
        const float4 k1 = *(const float4*)&h_lds[base + 4];
        base += 8;
        const f2 k01 = {k0.x, k0.y}, k23 = {k0.z, k0.w};
        const f2 k45 = {k1.x, k1.y}, k67 = {k1.z, k1.w};
#pragma unroll
        for (int qq = 0; qq < 4; ++qq) {
            const f2 d0 = qv[qq][0] * k01 + qv[qq][1] * k23;
            const f2 d1 = qv[qq][2] * k45 + qv[qq][3] * k67;
            const float e0 = __builtin_amdgcn_exp2f(d0.x + d0.y);
            const float e1 = __builtin_amdgcn_exp2f(d1.x + d1.y);
            l0[qq] += e0;
            l1[qq] += e1;
            const f2 e0v = {e0, e0}, e1v = {e1, e1};
            a01[qq] += e0v * k01;
            a23[qq] += e0v * k23;
            a45[qq] += e1v * k45;
            a67[qq] += e1v * k67;
        }
    }

    // ---- 64-lane butterfly over 4 queries x 10 partials ----
    float red[40];
#pragma unroll
    for (int qq = 0; qq < 4; ++qq) {
        red[qq * 10 + 0] = l0[qq];
        red[qq * 10 + 1] = l1[qq];
        red[qq * 10 + 2] = a01[qq].x;
        red[qq * 10 + 3] = a01[qq].y;
        red[qq * 10 + 4] = a23[qq].x;
        red[qq * 10 + 5] = a23[qq].y;
        red[qq * 10 + 6] = a45[qq].x;
        red[qq * 10 + 7] = a45[qq].y;
        red[qq * 10 + 8] = a67[qq].x;
        red[qq * 10 + 9] = a67[qq].y;
    }
#pragma unroll
    for (int m = 1; m < 64; m <<= 1) {
#pragma unroll
        for (int j = 0; j < 40; ++j) red[j] += __shfl_xor(red[j], m);
    }

    // lanes 0..3 each finalize query qbase+lane (branch-free query mux)
    float sel[10];
#pragma unroll
    for (int j = 0; j < 10; ++j) {
        const float v01 = (lane & 1) ? red[10 + j] : red[j];
        const float v23 = (lane & 1) ? red[30 + j] : red[20 + j];
        sel[j] = (lane & 2) ? v23 : v01;
    }
    if (lane < 4) {
        const float inv0 = 1.0f / sel[0];
        const float inv1 = 1.0f / sel[1];
        float y[8];
#pragma unroll
        for (int d = 0; d < 4; ++d) {
            y[d]     = sel[2 + d] * inv0;
            y[4 + d] = sel[6 + d] * inv1;
        }
        float o[8];
        qrow(th, y, o);
        float4* op = (float4*)(out + ((size_t)(b * SEQ + qbase + lane)) * 8);
        op[0] = make_float4(o[0], o[1], o[2], o[3]);
        op[1] = make_float4(o[4], o[5], o[6], o[7]);
    }
}

extern "C" void kernel_launch(void* const* d_in, const int* in_sizes, int n_in,
                              void* d_out, int out_size, void* d_ws, size_t ws_size,
                              hipStream_t stream) {
    const float* x     = (const float*)d_in[0];
    const float* theta = (const float*)d_in[1];
    float* out         = (float*)d_out;
    mhaq_fused<<<dim3(16 * 64), dim3(256), 0, stream>>>(x, theta, out);
}

// Round 5
// 66.466 us; speedup vs baseline: 1.0519x; 1.0519x over previous
//
#include <hip/hip_runtime.h>

#define SEQ 1024

typedef __attribute__((ext_vector_type(2))) float f2;

// h storage: row k = two 16B slots s=2k and s=2k+1; physical 16B-slot index
//   P(s) = s ^ ((s>>6)&7)   (word address = 4*P).
// Bijective (bits 0..2 XORed by untouched bits 6..8) -> NO row collisions
// (R4's wrapping additive pad was non-injective and corrupted h).
// Bank clusters (4-bank groups) = P&7:
//  - stage-2: 16 rows k = kh*512 + m*32 + i -> cluster (s&7)^(m&7): every
//    cluster hit exactly 2x -> 2-way, free (m136).
//  - stage-1: 64 consecutive rows/wave -> all 8 clusters 8-deep (optimal).
static __device__ __forceinline__ int slot_addr(int s) {
    return (s ^ ((s >> 6) & 7)) << 2;
}

// Closed-form qlayer for one token row y[0..7]:
// angles a = {y0+t0, y1+t1, y2+y3+t2, t3, y4+t4, y5+t5, y6+t6, y7+t7}
// c_w = cos(a_w); out[0] = c1..c7, out[w] = c0..cw (w>=1).
static __device__ __forceinline__ void qrow(const float th[8], const float y[8], float o[8]) {
    float a[8];
    a[0] = y[0] + th[0];
    a[1] = y[1] + th[1];
    a[2] = y[2] + y[3] + th[2];
    a[3] = th[3];
    a[4] = y[4] + th[4];
    a[5] = y[5] + th[5];
    a[6] = y[6] + th[6];
    a[7] = y[7] + th[7];
    float c[8];
#pragma unroll
    for (int w = 0; w < 8; ++w) c[w] = __cosf(a[w]);
    o[1] = c[0] * c[1];
#pragma unroll
    for (int w = 2; w < 8; ++w) o[w] = o[w - 1] * c[w];
    float s = c[7];
#pragma unroll
    for (int w = 6; w >= 1; --w) s *= c[w];
    o[0] = s;
}

// Fused qlayer -> 2-head attention (dk=4) -> qlayer.
// Grid: 512 blocks (16 batches x 32 query-tiles of 32), 256 threads,
// 2 blocks/CU. Wave: qs=wv>>1 query-set (16 q), kh=wv&1 key half (512 k);
// 4 groups of 16 lanes, group g register-blocks 4 queries (Qr=4), lane m
// covers 32 keys. All groups read the same key row -> LDS broadcast: a wave
// read presents only 16 distinct 16B slots (2/cluster) ~= 2 clk.
// Reduction: contiguous per-thread partial dump (10 ds_write_b128, stride 44
// words -> clusters 11t mod 8, bijective, optimal) then 320 collector units.
__global__ __launch_bounds__(256, 2) void mhaq_fused(const float* __restrict__ x,
                                                     const float* __restrict__ theta,
                                                     float* __restrict__ out) {
    // phase 1: h = 1024 rows x 2 slots = 8192 words (XOR-swizzled, no pad)
    // phase 2 (overlays h after barrier): partials 256 x 44 words = 11264
    // res: 32 q x 10 vals
    __shared__ __align__(16) float smem[11264 + 320];
    float* const res = smem + 11264;

    const int b   = blockIdx.x >> 5;         // batch
    const int qof = (blockIdx.x & 31) << 5;  // first query of this block's 32
    const int t   = threadIdx.x;

    float th[8];
#pragma unroll
    for (int w = 0; w < 8; ++w) th[w] = theta[w];

    // ---- Stage 1: h[b] (1024 x 8) into LDS ----
    const float4* xb = (const float4*)(x + (size_t)b * SEQ * 8);
    float4 v0[4], v1[4];
#pragma unroll
    for (int r = 0; r < 4; ++r) {
        const int k = t + (r << 8);
        v0[r] = xb[2 * k];
        v1[r] = xb[2 * k + 1];
    }
#pragma unroll
    for (int r = 0; r < 4; ++r) {
        const int k = t + (r << 8);
        const float y[8] = {v0[r].x, v0[r].y, v0[r].z, v0[r].w,
                            v1[r].x, v1[r].y, v1[r].z, v1[r].w};
        float o[8];
        qrow(th, y, o);
        *(float4*)&smem[slot_addr(2 * k)]     = make_float4(o[0], o[1], o[2], o[3]);
        *(float4*)&smem[slot_addr(2 * k + 1)] = make_float4(o[4], o[5], o[6], o[7]);
    }
    __syncthreads();

    // ---- Stage 2: inner attention loop ----
    const int lane = t & 63;
    const int wv   = t >> 6;
    const int qs   = wv >> 1;     // query-set 0/1
    const int kh   = wv & 1;      // key half 0/1
    const int g    = lane >> 4;   // query group 0..3
    const int m    = lane & 15;   // key sub-chunk 0..15
    const int q0   = qof + (qs << 4) + (g << 2);  // first of this lane's 4 queries

    const float qscale = 0.5f * 1.44269504f;  // 1/sqrt(dk) * log2(e)
    f2 qv[4][4];
#pragma unroll
    for (int qq = 0; qq < 4; ++qq) {
        const float4 qa = *(const float4*)&smem[slot_addr(2 * (q0 + qq))];      // broadcast
        const float4 qb = *(const float4*)&smem[slot_addr(2 * (q0 + qq) + 1)];  // broadcast
        qv[qq][0] = f2{qa.x, qa.y} * qscale;
        qv[qq][1] = f2{qa.z, qa.w} * qscale;
        qv[qq][2] = f2{qb.x, qb.y} * qscale;
        qv[qq][3] = f2{qb.z, qb.w} * qscale;
    }

    float l0[4] = {0.f, 0.f, 0.f, 0.f};
    float l1[4] = {0.f, 0.f, 0.f, 0.f};
    f2 a01[4], a23[4], a45[4], a67[4];
#pragma unroll
    for (int qq = 0; qq < 4; ++qq) {
        a01[qq] = f2{0.f, 0.f};
        a23[qq] = f2{0.f, 0.f};
        a45[qq] = f2{0.f, 0.f};
        a67[qq] = f2{0.f, 0.f};
    }

    const int kbase = (kh << 9) + (m << 5);  // this lane's 32-key chunk
#pragma unroll 4
    for (int i = 0; i < 32; ++i) {
        const int s0 = (kbase + i) << 1;
        const float4 k0 = *(const float4*)&smem[slot_addr(s0)];
        const float4 k1 = *(const float4*)&smem[slot_addr(s0 + 1)];
        const f2 k01 = {k0.x, k0.y}, k23 = {k0.z, k0.w};
        const f2 k45 = {k1.x, k1.y}, k67 = {k1.z, k1.w};
#pragma unroll
        for (int qq = 0; qq < 4; ++qq) {
            const f2 d0 = qv[qq][0] * k01 + qv[qq][1] * k23;
            const f2 d1 = qv[qq][2] * k45 + qv[qq][3] * k67;
            const float e0 = __builtin_amdgcn_exp2f(d0.x + d0.y);
            const float e1 = __builtin_amdgcn_exp2f(d1.x + d1.y);
            l0[qq] += e0;
            l1[qq] += e1;
            const f2 e0v = {e0, e0}, e1v = {e1, e1};
            a01[qq] += e0v * k01;
            a23[qq] += e0v * k23;
            a45[qq] += e1v * k45;
            a67[qq] += e1v * k67;
        }
    }
    __syncthreads();  // all waves done reading h -> safe to overlay partials

    // ---- partial dump: 40 floats/thread, contiguous, stride 44 words ----
    {
        float buf[40];
#pragma unroll
        for (int qq = 0; qq < 4; ++qq) {
            buf[qq * 10 + 0] = l0[qq];
            buf[qq * 10 + 1] = l1[qq];
            buf[qq * 10 + 2] = a01[qq].x;
            buf[qq * 10 + 3] = a01[qq].y;
            buf[qq * 10 + 4] = a23[qq].x;
            buf[qq * 10 + 5] = a23[qq].y;
            buf[qq * 10 + 6] = a45[qq].x;
            buf[qq * 10 + 7] = a45[qq].y;
            buf[qq * 10 + 8] = a67[qq].x;
            buf[qq * 10 + 9] = a67[qq].y;
        }
        float4* pp = (float4*)&smem[t * 44];  // 176 B stride, 16B-aligned
#pragma unroll
        for (int i = 0; i < 10; ++i) pp[i] = ((const float4*)buf)[i];
    }
    __syncthreads();

    // ---- combine: 320 units (32 q x 10 j), each sums 32 contribs ----
    for (int u = t; u < 320; u += 256) {
        const int q  = u / 10;
        const int j  = u - q * 10;
        const int uqs = q >> 4, ug = (q >> 2) & 3, uqq = q & 3;
        // contributing threads: wv in {2*uqs, 2*uqs+1}, lanes ug*16 + m
        const int base = ((uqs << 7) + (ug << 4)) * 44 + uqq * 10 + j;
        float s = 0.f;
#pragma unroll
        for (int mm = 0; mm < 16; ++mm)
            s += smem[base + mm * 44] + smem[base + (64 + mm) * 44];
        res[q * 10 + j] = s;
    }
    __syncthreads();

    // ---- epilogue: thread q < 32 finalizes query qof+q ----
    if (t < 32) {
        const float* r = &res[t * 10];
        const float inv0 = 1.0f / r[0];
        const float inv1 = 1.0f / r[1];
        const float y[8] = {r[2] * inv0, r[3] * inv0, r[4] * inv0, r[5] * inv0,
                            r[6] * inv1, r[7] * inv1, r[8] * inv1, r[9] * inv1};
        float o[8];
        qrow(th, y, o);
        float4* op = (float4*)(out + ((size_t)(b * SEQ + qof + t)) * 8);
        op[0] = make_float4(o[0], o[1], o[2], o[3]);
        op[1] = make_float4(o[4], o[5], o[6], o[7]);
    }
}

extern "C" void kernel_launch(void* const* d_in, const int* in_sizes, int n_in,
                              void* d_out, int out_size, void* d_ws, size_t ws_size,
                              hipStream_t stream) {
    const float* x     = (const float*)d_in[0];
    const float* theta = (const float*)d_in[1];
    float* out         = (float*)d_out;
    mhaq_fused<<<dim3(512), dim3(256), 0, stream>>>(x, theta, out);
}